// Round 5
// baseline (262.571 us; speedup 1.0000x reference)
//
#include <hip/hip_runtime.h>

#define K_TAPS   61
#define R_OUT    16
#define BLOCK    256
#define TILE_OUT (BLOCK * R_OUT)            // 4096 outputs per block
#define WIN      (R_OUT + K_TAPS - 1)       // 76 floats = 19 float4 (exact)

__global__ __launch_bounds__(BLOCK)
void SpikeToCalcium_conv1d_kernel(const float* __restrict__ u,
                                  const float* __restrict__ kern,
                                  float* __restrict__ out,
                                  int L, int M, long long total_in)
{
    const int t    = threadIdx.x;
    const int row  = blockIdx.y;
    const int base = blockIdx.x * TILE_OUT + t * R_OUT;   // %16 == 0
    if (base >= M) return;                                // tail waves exit

    const long long g = (long long)row * L + base;        // 16B-aligned (L%4==0)

    // ---- Load the full 76-float window into registers: 19 independent
    // float4 loads, one waitcnt, no LDS, no barrier. Over-read into the
    // next row only feeds masked-out outputs; guard only the buffer end.
    float w[WIN];
    if (g + WIN <= total_in) {
#pragma unroll
        for (int i = 0; i < WIN / 4; ++i) {
            const float4 v = *reinterpret_cast<const float4*>(u + g + 4 * i);
            w[4 * i + 0] = v.x; w[4 * i + 1] = v.y;
            w[4 * i + 2] = v.z; w[4 * i + 3] = v.w;
        }
    } else {                                              // last row's tail only
#pragma unroll
        for (int i = 0; i < WIN; ++i)
            w[i] = (g + i < total_in) ? u[g + i] : 0.0f;
    }

    float acc[R_OUT];
#pragma unroll
    for (int r = 0; r < R_OUT; ++r) acc[r] = 0.0f;

    // ---- 61x16 fully-static FMA block. Tap index is wave-uniform ->
    // scalar s_load into SGPRs; v_fmac_f32 takes the tap as its one SGPR
    // operand. No register shifting, no per-step LDS dependency chain.
#pragma unroll
    for (int k = 0; k < K_TAPS; ++k) {
        const float kv = kern[K_TAPS - 1 - k];
#pragma unroll
        for (int r = 0; r < R_OUT; ++r)
            acc[r] = fmaf(w[r + k], kv, acc[r]);
    }

    // ---- Store 16 outputs as 4 float4 (M%4==0 and base%16==0 -> aligned).
    const long long o = (long long)row * M + base;
    if (base + R_OUT <= M) {
#pragma unroll
        for (int i = 0; i < R_OUT / 4; ++i) {
            const float4 v = make_float4(acc[4 * i + 0], acc[4 * i + 1],
                                         acc[4 * i + 2], acc[4 * i + 3]);
            *reinterpret_cast<float4*>(out + o + 4 * i) = v;
        }
    } else {                                              // row-tail mask
#pragma unroll
        for (int r = 0; r < R_OUT; ++r)
            if (base + r < M) out[o + r] = acc[r];
    }
}

extern "C" void kernel_launch(void* const* d_in, const int* in_sizes, int n_in,
                              void* d_out, int out_size, void* d_ws, size_t ws_size,
                              hipStream_t stream) {
    const float* u    = (const float*)d_in[0];
    const float* kern = (const float*)d_in[1];
    float*       out  = (float*)d_out;

    const long long total_in = (long long)in_sizes[0];
    // total_in = R*L, out_size = R*(L-K+1)  =>  R = (total_in - out_size)/(K-1)
    const int ROWS = (int)((total_in - (long long)out_size) / (K_TAPS - 1)); // 1024
    const int L    = (int)(total_in / ROWS);                                 // 30000
    const int M    = L - K_TAPS + 1;                                         // 29940

    const int blocks_per_row = (M + TILE_OUT - 1) / TILE_OUT;  // 8
    dim3 grid(blocks_per_row, ROWS);
    SpikeToCalcium_conv1d_kernel<<<grid, BLOCK, 0, stream>>>(
        u, kern, out, L, M, total_in);
}